// Round 8
// baseline (166.783 us; speedup 1.0000x reference)
//
#include <hip/hip_runtime.h>

// GAT layer: B=8, N=2048, Fin=Fout=64.
// k1: h = input@W (fp32) + s1/s2 + split-bf16 transposed h (hi/lo planes)
// k2: flash-style masked softmax attention, PV via 3x mfma_16x16x32_bf16 (split-bf16)

typedef __attribute__((ext_vector_type(8))) short s16x8;
typedef __attribute__((ext_vector_type(8))) unsigned short u16x8;
typedef __attribute__((ext_vector_type(4))) float f32x4;

#define ALPHA 0.2f
#define NEGINF -9000000000000000.0f

__device__ __forceinline__ unsigned short f2bf(float f) {
  unsigned int x = __float_as_uint(f);
  x += 0x7fffu + ((x >> 16) & 1u);   // RNE (no NaN inputs here)
  return (unsigned short)(x >> 16);
}
__device__ __forceinline__ float bf2f(unsigned short h) {
  return __uint_as_float(((unsigned int)h) << 16);
}

// ---------------- Kernel 1: prep ----------------
// grid (32, 8), block 256. Block handles 64 rows of one batch.
__global__ __launch_bounds__(256) void gat_prep(
    const float* __restrict__ inp, const float* __restrict__ W,
    const float* __restrict__ a,
    unsigned short* __restrict__ hT_hi, unsigned short* __restrict__ hT_lo,
    float* __restrict__ s1, float* __restrict__ s2)
{
  const int b  = blockIdx.y;
  const int n0 = blockIdx.x * 64;
  const int t  = threadIdx.x;

  __shared__ float Wl[64 * 64];
  __shared__ float il[64 * 64];
  __shared__ float ht[64 * 65];   // h tile, padded stride 65

  for (int idx = t; idx < 4096; idx += 256) Wl[idx] = W[idx];
  const float* ib = inp + ((size_t)b * 2048 + n0) * 64;
  for (int idx = t; idx < 4096; idx += 256) il[idx] = ib[idx];
  __syncthreads();

  const int w = t >> 6, lane = t & 63;
  // W column (for this lane's output feature) in registers
  float wreg[64];
  #pragma unroll
  for (int k = 0; k < 64; ++k) wreg[k] = Wl[k * 64 + lane];
  const float a1 = a[lane], a2 = a[64 + lane];

  for (int r8 = 0; r8 < 16; ++r8) {
    const int row = w * 16 + r8;
    float acc = 0.f;
    #pragma unroll
    for (int k4 = 0; k4 < 16; ++k4) {
      float4 iv = *(const float4*)&il[row * 64 + k4 * 4];  // broadcast read
      acc += iv.x * wreg[k4 * 4 + 0];
      acc += iv.y * wreg[k4 * 4 + 1];
      acc += iv.z * wreg[k4 * 4 + 2];
      acc += iv.w * wreg[k4 * 4 + 3];
    }
    ht[row * 65 + lane] = acc;
    float p1 = acc * a1, p2 = acc * a2;
    #pragma unroll
    for (int off = 32; off; off >>= 1) {
      p1 += __shfl_xor(p1, off);
      p2 += __shfl_xor(p2, off);
    }
    if (lane == 0) {
      s1[b * 2048 + n0 + row] = p1;
      s2[b * 2048 + n0 + row] = p2;
    }
  }
  __syncthreads();

  // transposed split-bf16 write: thread t -> feature f = t>>2, 16 n's
  const int f = t >> 2, nl = (t & 3) * 16;
  u16x8 hi0, hi1, lo0, lo1;
  #pragma unroll
  for (int q = 0; q < 16; ++q) {
    float v = ht[(nl + q) * 65 + f];
    unsigned short hb = f2bf(v);
    float lov = v - bf2f(hb);
    unsigned short lb = f2bf(lov);
    if (q < 8) { hi0[q] = hb; lo0[q] = lb; }
    else       { hi1[q - 8] = hb; lo1[q - 8] = lb; }
  }
  size_t base = ((size_t)b * 64 + f) * 2048 + n0 + nl;
  *(u16x8*)(hT_hi + base)     = hi0;
  *(u16x8*)(hT_hi + base + 8) = hi1;
  *(u16x8*)(hT_lo + base)     = lo0;
  *(u16x8*)(hT_lo + base + 8) = lo1;
}

// ---------------- Kernel 2: masked flash attention ----------------
// grid (32, 8), block 256 = 4 waves; wave w owns 16 query rows; j-tiles of 32.
__global__ __launch_bounds__(256) void gat_attn(
    const int* __restrict__ adj,
    const unsigned short* __restrict__ hT_hi, const unsigned short* __restrict__ hT_lo,
    const float* __restrict__ s1, const float* __restrict__ s2,
    float* __restrict__ out)
{
  const int b  = blockIdx.y;
  const int i0 = blockIdx.x * 64;
  const int t  = threadIdx.x;
  const int w  = t >> 6, l = t & 63;
  const int r  = l & 15, g = l >> 4;

  __shared__ float s2l[2048];
  __shared__ unsigned short hhi[64 * 40];   // [f][j] tile, stride 40 (80B, 16B-aligned)
  __shared__ unsigned short hlo[64 * 40];

  for (int idx = t * 4; idx < 2048; idx += 1024)
    *(float4*)&s2l[idx] = *(const float4*)&s2[b * 2048 + idx];

  const int irow = i0 + w * 16 + r;
  const float s1r = s1[b * 2048 + irow];
  const int* adjp = adj + (size_t)irow * 2048 + g * 8;
  const unsigned short* ghi = hT_hi + (size_t)b * 64 * 2048;
  const unsigned short* glo = hT_lo + (size_t)b * 64 * 2048;

  float m = NEGINF, lsum = 0.f;
  f32x4 acc[4];
  #pragma unroll
  for (int c = 0; c < 4; ++c) acc[c] = (f32x4){0.f, 0.f, 0.f, 0.f};

  const int sf = t >> 2, sj = (t & 3) * 8;   // staging: thread -> (feature, j-chunk)

  for (int j0 = 0; j0 < 2048; j0 += 32) {
    __syncthreads();   // previous tile's LDS reads done before overwrite
    *(u16x8*)&hhi[sf * 40 + sj] = *(const u16x8*)(ghi + sf * 2048 + j0 + sj);
    *(u16x8*)&hlo[sf * 40 + sj] = *(const u16x8*)(glo + sf * 2048 + j0 + sj);
    __syncthreads();

    // 8 scores per lane: j = j0 + g*8 + e  (MFMA A-fragment layout, contiguous-8)
    int4 ad0 = *(const int4*)(adjp + j0);
    int4 ad1 = *(const int4*)(adjp + j0 + 4);
    float4 sv0 = *(const float4*)&s2l[j0 + g * 8];
    float4 sv1 = *(const float4*)&s2l[j0 + g * 8 + 4];
    float e[8];
    e[0] = s1r + sv0.x; e[1] = s1r + sv0.y; e[2] = s1r + sv0.z; e[3] = s1r + sv0.w;
    e[4] = s1r + sv1.x; e[5] = s1r + sv1.y; e[6] = s1r + sv1.z; e[7] = s1r + sv1.w;
    const int adv[8] = {ad0.x, ad0.y, ad0.z, ad0.w, ad1.x, ad1.y, ad1.z, ad1.w};
    #pragma unroll
    for (int k = 0; k < 8; ++k) {
      float le = fmaxf(e[k], ALPHA * e[k]);          // LeakyReLU
      e[k] = adv[k] > 0 ? le : NEGINF;               // adjacency mask
    }

    // online softmax (state replicated across the 4 lane-groups of each row)
    float tm = e[0];
    #pragma unroll
    for (int k = 1; k < 8; ++k) tm = fmaxf(tm, e[k]);
    tm = fmaxf(tm, __shfl_xor(tm, 16));
    tm = fmaxf(tm, __shfl_xor(tm, 32));
    const float mnew  = fmaxf(m, tm);
    const float scale = __expf(m - mnew);            // exp(0)=1 when both NEGINF
    float p[8], ts = 0.f;
    #pragma unroll
    for (int k = 0; k < 8; ++k) { p[k] = __expf(e[k] - mnew); ts += p[k]; }
    ts += __shfl_xor(ts, 16);
    ts += __shfl_xor(ts, 32);
    lsum = lsum * scale + ts;
    m = mnew;

    // rescale accumulator (acc row = g*4+q lives on source lane g*4+q)
    float sc[4];
    #pragma unroll
    for (int q = 0; q < 4; ++q) sc[q] = __shfl(scale, g * 4 + q);
    #pragma unroll
    for (int c = 0; c < 4; ++c) {
      #pragma unroll
      for (int q = 0; q < 4; ++q) acc[c][q] *= sc[q];
    }

    // split-bf16 p fragments
    s16x8 phi, plo;
    #pragma unroll
    for (int k = 0; k < 8; ++k) {
      unsigned short hb = f2bf(p[k]);
      phi[k] = (short)hb;
      plo[k] = (short)f2bf(p[k] - bf2f(hb));
    }

    // PV: 4 feature chunks x 3 MFMAs (drop lo*lo term)
    #pragma unroll
    for (int c = 0; c < 4; ++c) {
      s16x8 bh = *(const s16x8*)&hhi[(c * 16 + r) * 40 + g * 8];
      s16x8 bl = *(const s16x8*)&hlo[(c * 16 + r) * 40 + g * 8];
      acc[c] = __builtin_amdgcn_mfma_f32_16x16x32_bf16(phi, bh, acc[c], 0, 0, 0);
      acc[c] = __builtin_amdgcn_mfma_f32_16x16x32_bf16(phi, bl, acc[c], 0, 0, 0);
      acc[c] = __builtin_amdgcn_mfma_f32_16x16x32_bf16(plo, bh, acc[c], 0, 0, 0);
    }
  }

  // epilogue: normalize, ELU, store
  float inv[4];
  #pragma unroll
  for (int q = 0; q < 4; ++q) inv[q] = 1.f / __shfl(lsum, g * 4 + q);
  #pragma unroll
  for (int c = 0; c < 4; ++c) {
    #pragma unroll
    for (int q = 0; q < 4; ++q) {
      float v = acc[c][q] * inv[q];
      v = v > 0.f ? v : __expf(v) - 1.f;   // ELU (alpha=1)
      out[((size_t)b * 2048 + i0 + w * 16 + g * 4 + q) * 64 + c * 16 + r] = v;
    }
  }
}

extern "C" void kernel_launch(void* const* d_in, const int* in_sizes, int n_in,
                              void* d_out, int out_size, void* d_ws, size_t ws_size,
                              hipStream_t stream) {
  (void)in_sizes; (void)n_in; (void)out_size; (void)ws_size;
  const float* inp = (const float*)d_in[0];
  const int*   adj = (const int*)d_in[1];
  const float* W   = (const float*)d_in[2];
  const float* a   = (const float*)d_in[3];
  float* out = (float*)d_out;

  char* ws = (char*)d_ws;
  unsigned short* hT_hi = (unsigned short*)ws;                    // 2 MB
  unsigned short* hT_lo = (unsigned short*)(ws + (2u << 20));     // 2 MB
  float* s1 = (float*)(ws + (4u << 20));                          // 64 KB
  float* s2 = (float*)(ws + (4u << 20) + (64u << 10));            // 64 KB

  dim3 grid(32, 8);
  gat_prep<<<grid, 256, 0, stream>>>(inp, W, a, hT_hi, hT_lo, s1, s2);
  gat_attn<<<grid, 256, 0, stream>>>(adj, hT_hi, hT_lo, s1, s2, out);
}

// Round 11
// 156.093 us; speedup vs baseline: 1.0685x; 1.0685x over previous
//
#include <hip/hip_runtime.h>

// GAT layer: B=8, N=2048, Fin=Fout=64.
// k1: h = input@W (fp32) + s1/s2 + split-bf16 transposed h (hi/lo planes)   [unchanged]
// k2: flash-decoding attention: 4 waves split j-range (512 each), no barriers in
//     main loop, B-frags direct from L2, LDS combine of partial (m,l,acc).

typedef __attribute__((ext_vector_type(8))) short s16x8;
typedef __attribute__((ext_vector_type(8))) unsigned short u16x8;
typedef __attribute__((ext_vector_type(4))) float f32x4;

#define ALPHA 0.2f
#define NEGINF -9000000000000000.0f

__device__ __forceinline__ unsigned short f2bf(float f) {
  unsigned int x = __float_as_uint(f);
  x += 0x7fffu + ((x >> 16) & 1u);   // RNE (no NaN inputs here)
  return (unsigned short)(x >> 16);
}
__device__ __forceinline__ float bf2f(unsigned short h) {
  return __uint_as_float(((unsigned int)h) << 16);
}

// ---------------- Kernel 1: prep (unchanged) ----------------
__global__ __launch_bounds__(256) void gat_prep(
    const float* __restrict__ inp, const float* __restrict__ W,
    const float* __restrict__ a,
    unsigned short* __restrict__ hT_hi, unsigned short* __restrict__ hT_lo,
    float* __restrict__ s1, float* __restrict__ s2)
{
  const int b  = blockIdx.y;
  const int n0 = blockIdx.x * 64;
  const int t  = threadIdx.x;

  __shared__ float Wl[64 * 64];
  __shared__ float il[64 * 64];
  __shared__ float ht[64 * 65];   // h tile, padded stride 65

  for (int idx = t; idx < 4096; idx += 256) Wl[idx] = W[idx];
  const float* ib = inp + ((size_t)b * 2048 + n0) * 64;
  for (int idx = t; idx < 4096; idx += 256) il[idx] = ib[idx];
  __syncthreads();

  const int w = t >> 6, lane = t & 63;
  float wreg[64];
  #pragma unroll
  for (int k = 0; k < 64; ++k) wreg[k] = Wl[k * 64 + lane];
  const float a1 = a[lane], a2 = a[64 + lane];

  for (int r8 = 0; r8 < 16; ++r8) {
    const int row = w * 16 + r8;
    float acc = 0.f;
    #pragma unroll
    for (int k4 = 0; k4 < 16; ++k4) {
      float4 iv = *(const float4*)&il[row * 64 + k4 * 4];
      acc += iv.x * wreg[k4 * 4 + 0];
      acc += iv.y * wreg[k4 * 4 + 1];
      acc += iv.z * wreg[k4 * 4 + 2];
      acc += iv.w * wreg[k4 * 4 + 3];
    }
    ht[row * 65 + lane] = acc;
    float p1 = acc * a1, p2 = acc * a2;
    #pragma unroll
    for (int off = 32; off; off >>= 1) {
      p1 += __shfl_xor(p1, off);
      p2 += __shfl_xor(p2, off);
    }
    if (lane == 0) {
      s1[b * 2048 + n0 + row] = p1;
      s2[b * 2048 + n0 + row] = p2;
    }
  }
  __syncthreads();

  const int f = t >> 2, nl = (t & 3) * 16;
  u16x8 hi0, hi1, lo0, lo1;
  #pragma unroll
  for (int q = 0; q < 16; ++q) {
    float v = ht[(nl + q) * 65 + f];
    unsigned short hb = f2bf(v);
    float lov = v - bf2f(hb);
    unsigned short lb = f2bf(lov);
    if (q < 8) { hi0[q] = hb; lo0[q] = lb; }
    else       { hi1[q - 8] = hb; lo1[q - 8] = lb; }
  }
  size_t base = ((size_t)b * 64 + f) * 2048 + n0 + nl;
  *(u16x8*)(hT_hi + base)     = hi0;
  *(u16x8*)(hT_hi + base + 8) = hi1;
  *(u16x8*)(hT_lo + base)     = lo0;
  *(u16x8*)(hT_lo + base + 8) = lo1;
}

// ---------------- Kernel 2: flash-decoding masked attention ----------------
// grid (128, 8), block 256 = 4 waves. Block owns 16 query rows; wave w owns
// j in [w*512, w*512+512), 16 tiles of 32. No barriers in main loop.
__global__ __launch_bounds__(256) void gat_attn(
    const int* __restrict__ adj,
    const unsigned short* __restrict__ hT_hi, const unsigned short* __restrict__ hT_lo,
    const float* __restrict__ s1, const float* __restrict__ s2,
    float* __restrict__ out)
{
  const int b  = blockIdx.y;
  const int i0 = blockIdx.x * 16;
  const int t  = threadIdx.x;
  const int w  = t >> 6, l = t & 63;
  const int r  = l & 15, g = l >> 4;

  __shared__ float s2l[2048];
  __shared__ float accbuf[4][16][64];   // [wave][row][feat]
  __shared__ float mlbuf[4][16][2];     // [wave][row][{m,l}]

  for (int idx = t * 4; idx < 2048; idx += 1024)
    *(float4*)&s2l[idx] = *(const float4*)&s2[b * 2048 + idx];
  __syncthreads();   // all waves read the full s2l range staged by the block

  const int irow = i0 + r;
  const float s1r = s1[b * 2048 + irow];
  const int* adjp = adj + (size_t)irow * 2048 + g * 8;
  const unsigned short* ghi = hT_hi + (size_t)b * 64 * 2048;
  const unsigned short* glo = hT_lo + (size_t)b * 64 * 2048;

  float m = NEGINF, lsum = 0.f;
  f32x4 acc[4];
  #pragma unroll
  for (int c = 0; c < 4; ++c) acc[c] = (f32x4){0.f, 0.f, 0.f, 0.f};

  const int jw0 = w * 512;
  // 1-deep adj prefetch (L3-latency loads consumed at iteration top)
  int4 ad0 = *(const int4*)(adjp + jw0);
  int4 ad1 = *(const int4*)(adjp + jw0 + 4);

  for (int it = 0; it < 16; ++it) {
    const int j0 = jw0 + it * 32;
    const int jn = (it < 15) ? j0 + 32 : j0;   // clamp: last iter re-loads self
    int4 nad0 = *(const int4*)(adjp + jn);
    int4 nad1 = *(const int4*)(adjp + jn + 4);

    // 8 scores per lane: j = j0 + g*8 + e (MFMA A-fragment layout)
    float4 sv0 = *(const float4*)&s2l[j0 + g * 8];
    float4 sv1 = *(const float4*)&s2l[j0 + g * 8 + 4];
    float e[8];
    e[0] = s1r + sv0.x; e[1] = s1r + sv0.y; e[2] = s1r + sv0.z; e[3] = s1r + sv0.w;
    e[4] = s1r + sv1.x; e[5] = s1r + sv1.y; e[6] = s1r + sv1.z; e[7] = s1r + sv1.w;
    const int adv[8] = {ad0.x, ad0.y, ad0.z, ad0.w, ad1.x, ad1.y, ad1.z, ad1.w};
    #pragma unroll
    for (int k = 0; k < 8; ++k) {
      float le = fmaxf(e[k], ALPHA * e[k]);          // LeakyReLU
      e[k] = adv[k] > 0 ? le : NEGINF;               // adjacency mask
    }

    // online softmax (state replicated across the 4 lane-groups of each row)
    float tm = e[0];
    #pragma unroll
    for (int k = 1; k < 8; ++k) tm = fmaxf(tm, e[k]);
    tm = fmaxf(tm, __shfl_xor(tm, 16));
    tm = fmaxf(tm, __shfl_xor(tm, 32));
    const float mnew  = fmaxf(m, tm);
    const float scale = __expf(m - mnew);            // exp(0)=1 when both NEGINF
    float p[8], ts = 0.f;
    #pragma unroll
    for (int k = 0; k < 8; ++k) { p[k] = __expf(e[k] - mnew); ts += p[k]; }
    ts += __shfl_xor(ts, 16);
    ts += __shfl_xor(ts, 32);
    lsum = lsum * scale + ts;
    m = mnew;

    // rescale accumulator (acc row = g*4+q lives on source lane g*4+q)
    float sc[4];
    #pragma unroll
    for (int q = 0; q < 4; ++q) sc[q] = __shfl(scale, g * 4 + q);
    #pragma unroll
    for (int c = 0; c < 4; ++c) {
      #pragma unroll
      for (int q = 0; q < 4; ++q) acc[c][q] *= sc[q];
    }

    // split-bf16 p fragments
    s16x8 phi, plo;
    #pragma unroll
    for (int k = 0; k < 8; ++k) {
      unsigned short hb = f2bf(p[k]);
      phi[k] = (short)hb;
      plo[k] = (short)f2bf(p[k] - bf2f(hb));
    }

    // PV: B-frags straight from global (h planes are 4 MB total -> L2-resident)
    #pragma unroll
    for (int c = 0; c < 4; ++c) {
      const size_t fo = (size_t)(c * 16 + r) * 2048 + j0 + g * 8;
      s16x8 bh = *(const s16x8*)(ghi + fo);
      s16x8 bl = *(const s16x8*)(glo + fo);
      acc[c] = __builtin_amdgcn_mfma_f32_16x16x32_bf16(phi, bh, acc[c], 0, 0, 0);
      acc[c] = __builtin_amdgcn_mfma_f32_16x16x32_bf16(phi, bl, acc[c], 0, 0, 0);
      acc[c] = __builtin_amdgcn_mfma_f32_16x16x32_bf16(plo, bh, acc[c], 0, 0, 0);
    }

    ad0 = nad0; ad1 = nad1;
  }

  // publish partial state
  if (l < 16) { mlbuf[w][r][0] = m; mlbuf[w][r][1] = lsum; }
  #pragma unroll
  for (int c = 0; c < 4; ++c) {
    #pragma unroll
    for (int q = 0; q < 4; ++q) accbuf[w][g * 4 + q][c * 16 + r] = acc[c][q];
  }
  __syncthreads();

  // combine: thread t -> (row = t>>4, feature quad = (t&15)*4); 256 = 16x16 exact
  const int row = t >> 4, fb = (t & 15) * 4;
  float mw[4], lw[4];
  #pragma unroll
  for (int v = 0; v < 4; ++v) { mw[v] = mlbuf[v][row][0]; lw[v] = mlbuf[v][row][1]; }
  float M = fmaxf(fmaxf(mw[0], mw[1]), fmaxf(mw[2], mw[3]));
  float L = 0.f, wx[4];
  #pragma unroll
  for (int v = 0; v < 4; ++v) { wx[v] = __expf(mw[v] - M); L += lw[v] * wx[v]; }
  float4 o = {0.f, 0.f, 0.f, 0.f};
  #pragma unroll
  for (int v = 0; v < 4; ++v) {
    float4 av = *(const float4*)&accbuf[v][row][fb];
    o.x += av.x * wx[v]; o.y += av.y * wx[v];
    o.z += av.z * wx[v]; o.w += av.w * wx[v];
  }
  const float invL = 1.f / L;
  float ov[4] = {o.x * invL, o.y * invL, o.z * invL, o.w * invL};
  #pragma unroll
  for (int k = 0; k < 4; ++k) ov[k] = ov[k] > 0.f ? ov[k] : __expf(ov[k]) - 1.f; // ELU
  float4 res = {ov[0], ov[1], ov[2], ov[3]};
  *(float4*)&out[((size_t)b * 2048 + i0 + row) * 64 + fb] = res;
}

extern "C" void kernel_launch(void* const* d_in, const int* in_sizes, int n_in,
                              void* d_out, int out_size, void* d_ws, size_t ws_size,
                              hipStream_t stream) {
  (void)in_sizes; (void)n_in; (void)out_size; (void)ws_size;
  const float* inp = (const float*)d_in[0];
  const int*   adj = (const int*)d_in[1];
  const float* W   = (const float*)d_in[2];
  const float* a   = (const float*)d_in[3];
  float* out = (float*)d_out;

  char* ws = (char*)d_ws;
  unsigned short* hT_hi = (unsigned short*)ws;                    // 2 MB
  unsigned short* hT_lo = (unsigned short*)(ws + (2u << 20));     // 2 MB
  float* s1 = (float*)(ws + (4u << 20));                          // 64 KB
  float* s2 = (float*)(ws + (4u << 20) + (64u << 10));            // 64 KB

  gat_prep<<<dim3(32, 8), 256, 0, stream>>>(inp, W, a, hT_hi, hT_lo, s1, s2);
  gat_attn<<<dim3(128, 8), 256, 0, stream>>>(adj, hT_hi, hT_lo, s1, s2, out);
}